// Round 6
// baseline (2099.689 us; speedup 1.0000x reference)
//
#include <hip/hip_runtime.h>
#include <hip/hip_bf16.h>
#include <stdint.h>

// ---------------------------------------------------------------------------
// BasisCustBiLSTM: per-sample basis-mixed BiLSTM.
//   k_meta / k_xbf / k_whhp / k_bias / k_mixwih / k_gemm : prep (unchanged)
//   k_recur R11 = R10 with the reader-side storm thinned; producer path is
//     R10 verbatim (fused tagged record {h01,h23,tag,0}, ONE sc0sc1 store
//     from the cell wave, no drain, no flags).
//     (a) tag-only poll rounds: rounds load only the 4-B tag of each needed
//         record (32 B/lane/round vs 512 B) with s_sleep(16) backoff, then
//         ONE bulk payload pull once tags pass (embedded tags re-verified;
//         aligned 16-B sc0sc1 stores are single-transaction atomic, so the
//         verify passes immediately). Cuts the chip-wide poll storm ~25x
//         during the exact window the producer stores must land in.
//     (b) out-store batching: cell writes to an LDS ring outbuf[2][8][16][4];
//         wave 2 flushes 8 steps at once on (t&7)==7. Removes the per-step
//         8K-scattered-16B-write burst from the critical window.
//     Rationale: R5/R9/R10 pin at 5.5 us/step across 3 structures; raw
//     fabric RT is ~0.4 us, so the excess is synchronized-burst queueing
//     (max-over-256-blocks tail), not latency. R6/R8 thinned polls but ALSO
//     added producer RTs -- confounded. R11 separates the variables.
//     Safety: identical to R10 (payload pulled after tag-pass; overwrite of
//     buf[t&1] happens 2 steps later, gated by the same transitive poll).
// ---------------------------------------------------------------------------

typedef __attribute__((ext_vector_type(8))) __bf16 bf16x8;
typedef __attribute__((ext_vector_type(4))) __bf16 bf16x4;
typedef __attribute__((ext_vector_type(4))) float  f32x4;
typedef __attribute__((ext_vector_type(4))) unsigned u32x4;
typedef __attribute__((ext_vector_type(2))) unsigned u32x2;

#define TT 256
#define BBATCH 32

__device__ __forceinline__ __bf16 f2bf(float f){
  unsigned u = __builtin_bit_cast(unsigned, f);
  unsigned short r = (unsigned short)((u + 0x7fffu + ((u >> 16) & 1u)) >> 16);
  return __builtin_bit_cast(__bf16, r);
}
__device__ __forceinline__ float sigm(float x){
  x = fminf(fmaxf(x, -30.f), 30.f);
  return 1.f / (1.f + __expf(-x));
}
__device__ __forceinline__ float tanh_(float x){
  x = fminf(fmaxf(x, -15.f), 15.f);
  float e = __expf(2.f * x);
  return (e - 1.f) / (e + 1.f);
}

// --- coherent (MALL-level) access helpers: sc0 sc1 = bypass L1+L2 ----------
__device__ __forceinline__ u32x4 ld_b128_coh(const void* p){
  u32x4 v;
  asm volatile("global_load_dwordx4 %0, %1, off sc0 sc1"
               : "=v"(v) : "v"(p) : "memory");
  return v;
}
__device__ __forceinline__ unsigned ld_b32_coh(const void* p){
  unsigned v;
  asm volatile("global_load_dword %0, %1, off sc0 sc1"
               : "=v"(v) : "v"(p) : "memory");
  return v;
}
__device__ __forceinline__ void st_b128_coh(void* p, u32x4 v){
  asm volatile("global_store_dwordx4 %0, %1, off sc0 sc1"
               :: "v"(p), "v"(v) : "memory");
}

// ---------------------------------------------------------------------------
__global__ void k_meta(const void* __restrict__ mask,
                       const int* __restrict__ meta_a, const int* __restrict__ meta_c,
                       const float* __restrict__ emb_a, const float* __restrict__ emb_c,
                       const float* __restrict__ W1, const float* __restrict__ b1,
                       const float* __restrict__ W2,
                       float* __restrict__ c_out, int* __restrict__ len_out)
{
  __shared__ int s_bad;
  __shared__ float q_sh[32][128];
  __shared__ float hid[32][64];
  const int tid = threadIdx.x;
  if (tid == 0) s_bad = 0;
  __syncthreads();

  if (tid < 32){
    const unsigned char* m8 = (const unsigned char*)mask;
    int cnt = 0, seen0 = 0, bad = 0;
    for (int t = 0; t < TT; ++t){
      unsigned char v = m8[tid * TT + t];
      if (v > 1) bad = 1;
      if (v){ if (seen0) bad = 1; cnt++; } else seen0 = 1;
    }
    if (tid == 0 && cnt != TT) bad = 1;
    if (bad) atomicAdd(&s_bad, 1);
    len_out[tid] = cnt;
  }
  {
    int b = tid >> 3, p = tid & 7;
    int a = meta_a[b], c = meta_c[b];
    for (int i = 0; i < 16; ++i){
      int qi = p * 16 + i;
      q_sh[b][qi] = (qi < 64) ? emb_a[a * 64 + qi] : emb_c[c * 64 + (qi - 64)];
    }
  }
  __syncthreads();
  if (s_bad){
    if (tid < 32){
      const int* m32 = (const int*)mask;
      int cnt = 0;
      for (int t = 0; t < TT; ++t) if (m32[tid * TT + t]) cnt++;
      len_out[tid] = cnt;
    }
  }
  {
    int b = tid >> 3, kg = tid & 7;
    for (int k8 = 0; k8 < 8; ++k8){
      int k = kg * 8 + k8;
      float s = b1[k];
      for (int i = 0; i < 128; ++i) s += q_sh[b][i] * W1[i * 64 + k];
      hid[b][k] = tanhf(s);
    }
  }
  __syncthreads();
  if (tid < 32){
    float lg[8]; float mx = -1e30f;
    for (int n = 0; n < 8; ++n){
      float s = 0.f;
      for (int k = 0; k < 64; ++k) s += hid[tid][k] * W2[k * 8 + n];
      lg[n] = s; mx = fmaxf(mx, s);
    }
    float den = 0.f;
    for (int n = 0; n < 8; ++n){ lg[n] = expf(lg[n] - mx); den += lg[n]; }
    for (int n = 0; n < 8; ++n) c_out[tid * 8 + n] = lg[n] / den;
  }
}

// ---------------------------------------------------------------------------
__global__ void k_xbf(const float* __restrict__ x, __bf16* __restrict__ xb)
{
  int i = blockIdx.x * 256 + threadIdx.x;
  if (i >= 524288) return;
  f32x4 a = *(const f32x4*)(x + (size_t)i * 8);
  f32x4 b = *(const f32x4*)(x + (size_t)i * 8 + 4);
  bf16x8 o;
  #pragma unroll
  for (int j = 0; j < 4; ++j){ o[j] = f2bf(a[j]); o[4 + j] = f2bf(b[j]); }
  *(bf16x8*)(xb + (size_t)i * 8) = o;
}

// ---------------------------------------------------------------------------
__global__ void k_whhp(const float* __restrict__ whh_f, const float* __restrict__ whh_r,
                       __bf16* __restrict__ outp)
{
  int idx = blockIdx.x * 256 + threadIdx.x;
  int lane = idx & 63; int grp = idx >> 6;
  int n  = grp & 7;  grp >>= 3;
  int kt = grp & 3;  grp >>= 2;
  int wv = grp & 3;  grp >>= 2;
  int wg = grp & 127; int dir = (grp >> 7) & 1;
  int col = lane & 15, quad = lane >> 4;
  int gate = col >> 2, jj = col & 3;
  int g = gate * 512 + wg * 4 + jj;
  int k = (wv * 4 + kt) * 32 + quad * 8;
  const float* Wb = dir ? whh_r : whh_f;
  const float* s = Wb + ((size_t)n * 2048 + g) * 512 + k;
  f32x4 a = *(const f32x4*)s, b = *(const f32x4*)(s + 4);
  bf16x8 o;
  #pragma unroll
  for (int j = 0; j < 4; ++j){ o[j] = f2bf(a[j]); o[4 + j] = f2bf(b[j]); }
  *(bf16x8*)(outp + (size_t)idx * 8) = o;
}

// ---------------------------------------------------------------------------
__global__ void k_bias(const float* __restrict__ b_f, const float* __restrict__ b_r,
                       const float* __restrict__ cb, float* __restrict__ bm)
{
  int idx = blockIdx.x * 256 + threadIdx.x;
  int dir = idx >> 16; int b = (idx >> 11) & 31; int g = idx & 2047;
  const float* bb = dir ? b_r : b_f;
  float s = 0.f;
  #pragma unroll
  for (int n = 0; n < 8; ++n) s += cb[b * 8 + n] * bb[n * 2048 + g];
  bm[idx] = s;
}

// ---------------------------------------------------------------------------
__global__ void k_mixwih(const float* __restrict__ Wb, const float* __restrict__ cb,
                         __bf16* __restrict__ wmix)
{
  __shared__ float cs[256];
  int tid = threadIdx.x;
  cs[tid] = cb[tid];
  __syncthreads();
  int idx = blockIdx.x * 256 + tid;
  int g = idx >> 6, k8 = idx & 63;
  float src[8][8];
  #pragma unroll
  for (int n = 0; n < 8; ++n){
    const float* p = Wb + ((size_t)n * 2048 + g) * 512 + k8 * 8;
    f32x4 lo = *(const f32x4*)p, hi = *(const f32x4*)(p + 4);
    #pragma unroll
    for (int j = 0; j < 4; ++j){ src[n][j] = lo[j]; src[n][4 + j] = hi[j]; }
  }
  for (int b = 0; b < 32; ++b){
    float acc[8] = {0,0,0,0,0,0,0,0};
    #pragma unroll
    for (int n = 0; n < 8; ++n){
      float cn = cs[b * 8 + n];
      #pragma unroll
      for (int j = 0; j < 8; ++j) acc[j] += cn * src[n][j];
    }
    bf16x8 o;
    #pragma unroll
    for (int j = 0; j < 8; ++j) o[j] = f2bf(acc[j]);
    *(bf16x8*)(wmix + ((size_t)b * 2048 + g) * 512 + k8 * 8) = o;
  }
}

// ---------------------------------------------------------------------------
__global__ __launch_bounds__(256) void k_gemm(const __bf16* __restrict__ xb,
                                              const __bf16* __restrict__ wmix,
                                              float* __restrict__ xp)
{
  __shared__ __bf16 As[128][72];
  __shared__ __bf16 Bs[128][72];
  const int tid = threadIdx.x, lane = tid & 63, wv = tid >> 6;
  const int quad = lane >> 4, c16 = lane & 15;
  const int wm_ = wv >> 1, wn_ = wv & 1;
  const int b = blockIdx.x >> 5, tile = blockIdx.x & 31;
  const int m0 = (tile >> 4) * 128, n0 = (tile & 15) * 128;
  const __bf16* Ap = xb + (size_t)b * TT * 512;
  const __bf16* Bp = wmix + (size_t)b * 2048 * 512;
  float* Cp = xp + (size_t)b * TT * 2048;

  f32x4 acc[4][4];
  #pragma unroll
  for (int i = 0; i < 4; ++i)
    #pragma unroll
    for (int j = 0; j < 4; ++j) acc[i][j] = (f32x4){0,0,0,0};

  for (int k0 = 0; k0 < 512; k0 += 64){
    __syncthreads();
    #pragma unroll
    for (int it = 0; it < 4; ++it){
      int r = it * 32 + (tid >> 3), c = (tid & 7) * 8;
      *(bf16x8*)&As[r][c] = *(const bf16x8*)(Ap + (size_t)(m0 + r) * 512 + k0 + c);
      *(bf16x8*)&Bs[r][c] = *(const bf16x8*)(Bp + (size_t)(n0 + r) * 512 + k0 + c);
    }
    __syncthreads();
    #pragma unroll
    for (int kt = 0; kt < 2; ++kt){
      bf16x8 af[4], bfr[4];
      #pragma unroll
      for (int i = 0; i < 4; ++i){
        af[i]  = *(const bf16x8*)&As[wm_ * 64 + i * 16 + c16][kt * 32 + quad * 8];
        bfr[i] = *(const bf16x8*)&Bs[wn_ * 64 + i * 16 + c16][kt * 32 + quad * 8];
      }
      #pragma unroll
      for (int i = 0; i < 4; ++i)
        #pragma unroll
        for (int j = 0; j < 4; ++j)
          acc[i][j] = __builtin_amdgcn_mfma_f32_16x16x32_bf16(af[i], bfr[j], acc[i][j], 0, 0, 0);
    }
  }
  #pragma unroll
  for (int i = 0; i < 4; ++i)
    #pragma unroll
    for (int j = 0; j < 4; ++j){
      int colg = n0 + wn_ * 64 + j * 16 + c16;
      #pragma unroll
      for (int r = 0; r < 4; ++r){
        int row = m0 + wm_ * 64 + i * 16 + quad * 4 + r;
        Cp[(size_t)row * 2048 + colg] = acc[i][j][r];
      }
    }
}

// ---------------------------------------------------------------------------
// k_recur R11. Record buffers (256 KB total, at OFF_H):
//   rec[dir][chain g][buf][sample s 0..15][wg 0..127] = {h01, h23, tag, 0}
//     16 B; base offset ((dir*2+g)*2+buf) << 15.
// Protocol per chain (R5's): buf[t&1] with tag==t is the h input of step t.
//   Tag-0 zero records into buf0 at start; tag t+1 into buf[(t+1)&1] fired by
//   the cell wave right after computing h (shuffle-packed, one sc0sc1
//   dwordx4). Readers: tag-only poll rounds (4 B per record, s_sleep(16)
//   backoff) until all tags == t, then ONE bulk payload pull with embedded-
//   tag verification (16-B store atomicity -> passes immediately).
// Out rows buffered in LDS, flushed 8 steps at a time by wave 2.
// Launch/overwrite safety arguments unchanged from R9/R5.
// wg is XCD-swizzled (xproj/out 64B-line locality).
// ---------------------------------------------------------------------------
__global__ __launch_bounds__(256, 1) void k_recur(
    const __bf16* __restrict__ whhp,
    const float*  __restrict__ xproj,   // [2][32][256][2048]
    const float*  __restrict__ biasm,   // [2][32][2048]
    const float*  __restrict__ cb,      // [32][8]
    const int*    __restrict__ lens,    // [32]
    char* hrec,                         // record region (see above)
    float* __restrict__ out)            // [32][256][1024]
{
  const int tid = threadIdx.x, lane = tid & 63, wv = tid >> 6;
  const int quad = lane >> 4, c16 = lane & 15;
  const int bid = blockIdx.x, dir = bid >> 7;
  const int b7 = bid & 127;
  const int wg = ((b7 & 7) << 4) | (b7 >> 3);   // XCD-aware swizzle
  const int hidx0 = wg * 4;

  // basis-weight B fragments -> registers (logical-wg indexed)
  bf16x8 bfrag[4][8];
  {
    const __bf16* base = whhp + (size_t)((dir * 128 + wg) * 4 + wv) * 4 * (8 * 512);
    #pragma unroll
    for (int kt = 0; kt < 4; ++kt)
      #pragma unroll
      for (int n = 0; n < 8; ++n)
        bfrag[kt][n] = *(const bf16x8*)(base + (size_t)(kt * 8 + n) * 512 + lane * 8);
  }
  // c_batch columns for this lane's accumulator rows, per chain
  f32x4 ccv[2][8];
  #pragma unroll
  for (int g = 0; g < 2; ++g)
    #pragma unroll
    for (int n = 0; n < 8; ++n){
      f32x4 v;
      #pragma unroll
      for (int r = 0; r < 4; ++r) v[r] = cb[(g * 16 + quad * 4 + r) * 8 + n];
      ccv[g][n] = v;
    }

  // cell-thread state (tid < 64 = wave 0): sample s_ in chain, channel jj2
  const int s_ = tid >> 2, jj2 = tid & 3;
  float bias_gc[2][4] = {{0,0,0,0},{0,0,0,0}};
  int   mylen[2] = {0, 0};
  float cst[2] = {0.f, 0.f};
  if (tid < 64){
    #pragma unroll
    for (int g = 0; g < 2; ++g){
      #pragma unroll
      for (int gg = 0; gg < 4; ++gg)
        bias_gc[g][gg] = biasm[(size_t)(dir * 32 + g * 16 + s_) * 2048
                               + gg * 512 + hidx0 + jj2];
      mylen[g] = lens[g * 16 + s_];
    }
  }

  __shared__ float red[4][64][4];
  __shared__ float xg[32][4][4];
  __shared__ float outbuf[2][8][16][4];   // [chain][step&7][sample][ch]

  // init: lanes 192..223 publish zero-records (tag 0) into buf0, both chains
  if (tid >= 192 && tid < 224){
    int i = tid - 192, gi = i >> 4, sg = i & 15;
    u32x4 z = {0u, 0u, 0u, 0u};
    u32x4* wb = (u32x4*)(hrec + (((size_t)(dir * 2 + gi) * 2 + 0) << 15));
    st_b128_coh(wb + sg * 128 + wg, z);
  }

  // prefetch xproj for step 0 (normal cached load; waves 0-1)
  f32x4 pf = {0, 0, 0, 0};
  const int b_pf = tid >> 2, g_pf = tid & 3;
  if (tid < 128){
    int to0 = dir ? (TT - 1) : 0;
    pf = *(const f32x4*)(xproj + ((size_t)(dir * 32 + b_pf) * TT + to0) * 2048
                         + g_pf * 512 + hidx0);
  }

  // per-lane record indices (units of 16 B records), per kt: sample = c16,
  // channels (wv*4+kt)*32 + quad*8 .. +8 = records (wg0, wg0+1)
  int ridx[4];
  #pragma unroll
  for (int kt = 0; kt < 4; ++kt)
    ridx[kt] = c16 * 128 + (wv * 4 + kt) * 8 + quad * 2;

  for (int t = 0; t < TT; ++t){
    const int to = dir ? (TT - 1 - t) : t;
    const unsigned tgt = (unsigned)t;

    #pragma unroll
    for (int g = 0; g < 2; ++g){
      const char* rb_b = hrec + (((size_t)(dir * 2 + g) * 2 + (t & 1)) << 15);

      // ---- tag-only poll rounds (4 B per record) until all tags == t ----
      {
        int rnd = 0;
        while (true){
          unsigned tg0, tg1, tg2, tg3, tg4, tg5, tg6, tg7;
          tg0 = ld_b32_coh(rb_b + (size_t)ridx[0] * 16 + 8);
          tg1 = ld_b32_coh(rb_b + (size_t)(ridx[0] + 1) * 16 + 8);
          tg2 = ld_b32_coh(rb_b + (size_t)ridx[1] * 16 + 8);
          tg3 = ld_b32_coh(rb_b + (size_t)(ridx[1] + 1) * 16 + 8);
          tg4 = ld_b32_coh(rb_b + (size_t)ridx[2] * 16 + 8);
          tg5 = ld_b32_coh(rb_b + (size_t)(ridx[2] + 1) * 16 + 8);
          tg6 = ld_b32_coh(rb_b + (size_t)ridx[3] * 16 + 8);
          tg7 = ld_b32_coh(rb_b + (size_t)(ridx[3] + 1) * 16 + 8);
          asm volatile("s_waitcnt vmcnt(0)"
                       : "+v"(tg0), "+v"(tg1), "+v"(tg2), "+v"(tg3),
                         "+v"(tg4), "+v"(tg5), "+v"(tg6), "+v"(tg7)
                       :: "memory");
          unsigned bad = (tg0 ^ tgt) | (tg1 ^ tgt) | (tg2 ^ tgt) | (tg3 ^ tgt)
                       | (tg4 ^ tgt) | (tg5 ^ tgt) | (tg6 ^ tgt) | (tg7 ^ tgt);
          if (__all((int)(bad == 0u))) break;
          if (rnd >= 1) __builtin_amdgcn_s_sleep(16);   // ~1024 cyc backoff
          ++rnd;
        }
      }

      // ---- bulk payload pull (embedded tags verified; passes at once) ----
      u32x4 r0[4], r1[4];
      while (true){
        #pragma unroll
        for (int p = 0; p < 4; ++p){
          r0[p] = ld_b128_coh(rb_b + (size_t)ridx[p] * 16);
          r1[p] = ld_b128_coh(rb_b + (size_t)(ridx[p] + 1) * 16);
        }
        asm volatile("s_waitcnt vmcnt(0)"
                     : "+v"(r0[0]), "+v"(r0[1]), "+v"(r0[2]), "+v"(r0[3]),
                       "+v"(r1[0]), "+v"(r1[1]), "+v"(r1[2]), "+v"(r1[3])
                     :: "memory");
        unsigned bad = 0;
        #pragma unroll
        for (int p = 0; p < 4; ++p)
          bad |= (r0[p][2] ^ tgt) | (r1[p][2] ^ tgt);
        if (__all((int)(bad == 0u))) break;
      }
      bf16x8 af[4];
      #pragma unroll
      for (int p = 0; p < 4; ++p){
        u32x4 w = {r0[p][0], r0[p][1], r1[p][0], r1[p][1]};
        af[p] = __builtin_bit_cast(bf16x8, w);
      }

      // ---- MFMA: h(16 samples) x basis weights, mix over basis ----
      f32x4 acc[8];
      #pragma unroll
      for (int n = 0; n < 8; ++n) acc[n] = (f32x4){0,0,0,0};
      #pragma unroll
      for (int kt = 0; kt < 4; ++kt)
        #pragma unroll
        for (int n = 0; n < 8; ++n)
          acc[n] = __builtin_amdgcn_mfma_f32_16x16x32_bf16(af[kt], bfrag[kt][n], acc[n], 0, 0, 0);
      f32x4 mix = {0,0,0,0};
      #pragma unroll
      for (int n = 0; n < 8; ++n) mix += ccv[g][n] * acc[n];
      *(f32x4*)&red[wv][lane][0] = mix;
      if (g == 0 && tid < 128)
        *(f32x4*)&xg[b_pf][g_pf][0] = pf;   // xproj for ALL 32 samples, step t
      __syncthreads();   // S2: red/xg ready

      // ---- cell (wave 0): 16 samples x 4 channels; publish immediately ----
      if (tid < 64){
        const int qp = s_ >> 2, rg = s_ & 3;
        float gv[4];
        #pragma unroll
        for (int gg = 0; gg < 4; ++gg){
          int li = qp * 16 + gg * 4 + jj2;
          float s = red[0][li][rg] + red[1][li][rg]
                  + red[2][li][rg] + red[3][li][rg];
          gv[gg] = s + xg[g * 16 + s_][gg][jj2] + bias_gc[g][gg];
        }
        float i_ = sigm(gv[0]);
        float f_ = sigm(gv[1]);
        float g_ = tanh_(gv[2]);
        float o_ = sigm(gv[3]);
        bool valid = (to < mylen[g]);
        float cy = valid ? (f_ * cst[g] + i_ * g_) : 0.f;
        float hy = valid ? (o_ * tanh_(cy)) : 0.f;
        cst[g] = cy;
        outbuf[g][t & 7][s_][jj2] = hy;

        // shuffle-pack the 16 B record {h01,h23,tag,0} and fire it now
        unsigned hu = (unsigned)__builtin_bit_cast(unsigned short, f2bf(hy));
        unsigned hx = __shfl_xor(hu, 1, 64);
        unsigned dpair = (jj2 & 1) ? (hx | (hu << 16)) : (hu | (hx << 16));
        unsigned dothr = __shfl_xor(dpair, 2, 64);
        if (jj2 == 0){
          u32x4 rec = {dpair, dothr, (unsigned)(t + 1), 0u};
          u32x4* wb = (u32x4*)(hrec
                      + (((size_t)(dir * 2 + g) * 2 + ((t + 1) & 1)) << 15));
          st_b128_coh(wb + s_ * 128 + wg, rec);
        }
      }
      __syncthreads();   // S3: outbuf slot ready

      // ---- batched out flush: every 8 steps, wave 2 writes both chains ----
      if (g == 1 && (t & 7) == 7 && tid >= 128 && tid < 160){
        int i = tid - 128;              // 0..31
        int g2 = i >> 4, sg = i & 15;
        #pragma unroll
        for (int w = 0; w < 8; ++w){
          int tw = t - 7 + w;
          int tow = dir ? (TT - 1 - tw) : tw;
          *(f32x4*)(out + ((size_t)(g2 * 16 + sg) * TT + tow) * 1024
                    + dir * 512 + hidx0)
              = *(f32x4*)&outbuf[g2][w][sg][0];
        }
      }
      // ---- end of phase B: prefetch next step's xproj (cached) ----
      if (g == 1 && t < TT - 1 && tid < 128){
        int ton = dir ? (TT - 2 - t) : (t + 1);
        pf = *(const f32x4*)(xproj + ((size_t)(dir * 32 + b_pf) * TT + ton) * 2048
                             + g_pf * 512 + hidx0);
      }
    }
  }
}

// ---------------------------------------------------------------------------
extern "C" void kernel_launch(void* const* d_in, const int* in_sizes, int n_in,
                              void* d_out, int out_size, void* d_ws, size_t ws_size,
                              hipStream_t stream)
{
  const float* x      = (const float*)d_in[0];
  const void*  mask   = d_in[1];
  const int*   meta_a = (const int*)d_in[2];
  const int*   meta_c = (const int*)d_in[3];
  const float* emb_a  = (const float*)d_in[4];
  const float* emb_c  = (const float*)d_in[5];
  const float* P_W1   = (const float*)d_in[6];
  const float* P_b1   = (const float*)d_in[7];
  const float* P_W2   = (const float*)d_in[8];
  const float* W_ih   = (const float*)d_in[9];
  const float* W_hh   = (const float*)d_in[10];
  const float* bias_f = (const float*)d_in[11];
  const float* W_ih_r = (const float*)d_in[12];
  const float* W_hh_r = (const float*)d_in[13];
  const float* bias_r = (const float*)d_in[14];
  float* out = (float*)d_out;
  char* ws = (char*)d_ws;

  constexpr size_t OFF_C     = 0;           //   1 KB  c_batch
  constexpr size_t OFF_LEN   = 1024;        //  128 B  lengths
  constexpr size_t OFF_BIAS  = 4096;        //  512 KB mixed biases
  constexpr size_t OFF_H     = 528384;      //  256 KB tagged h records
  constexpr size_t OFF_WHHP  = 790528;      // 33.5 MB basis Whh fragments
  constexpr size_t OFF_XBF   = 34344960;    //  8.4 MB x bf16
  constexpr size_t OFF_WIHM  = 42733568;    //   67 MB mixed Wih (per-dir reuse)
  constexpr size_t OFF_XPROJ = 109842432;   //  134 MB xproj f32 (both dirs)
  constexpr size_t WS_NEED   = 244060160;
  if (ws_size < WS_NEED) return;

  float*   c_b   = (float*)(ws + OFF_C);
  int*     lens  = (int*)(ws + OFF_LEN);
  float*   biasm = (float*)(ws + OFF_BIAS);
  char*    hrec  = (char*)(ws + OFF_H);
  __bf16*  whhp  = (__bf16*)(ws + OFF_WHHP);
  __bf16*  xbf   = (__bf16*)(ws + OFF_XBF);
  __bf16*  wihm  = (__bf16*)(ws + OFF_WIHM);
  float*   xproj = (float*)(ws + OFF_XPROJ);

  k_meta<<<1, 256, 0, stream>>>(mask, meta_a, meta_c, emb_a, emb_c,
                                P_W1, P_b1, P_W2, c_b, lens);
  k_xbf<<<2048, 256, 0, stream>>>(x, xbf);
  k_whhp<<<8192, 256, 0, stream>>>(W_hh, W_hh_r, whhp);
  k_bias<<<512, 256, 0, stream>>>(bias_f, bias_r, c_b, biasm);
  for (int dir = 0; dir < 2; ++dir){
    k_mixwih<<<512, 256, 0, stream>>>(dir ? W_ih_r : W_ih, c_b, wihm);
    k_gemm<<<1024, 256, 0, stream>>>(xbf, wihm,
                                     xproj + (size_t)dir * 32 * TT * 2048);
  }
  k_recur<<<256, 256, 0, stream>>>(whhp, xproj, biasm, c_b, lens, hrec, out);
}

// Round 7
// 1289.232 us; speedup vs baseline: 1.6286x; 1.6286x over previous
//
#include <hip/hip_runtime.h>
#include <hip/hip_bf16.h>
#include <stdint.h>

// ---------------------------------------------------------------------------
// BasisCustBiLSTM: per-sample basis-mixed BiLSTM.
//   k_meta / k_xbf / k_whhp / k_bias / k_mixwih / k_gemm : prep (unchanged)
//   k_recur R12 = R9 exchange protocol with the per-step loop stripped to
//     poll + MFMA + cell ONLY:
//     (a) out accumulated in LDS ob[2][16][257][4] (128.5 KB), flushed once
//         after the t-loop -> removes 33.5 MB RFO + ~3x write-amp from the
//         steady state (R9 WRITE_SIZE 98.5 MB vs 33.5 ideal).
//     (b) xproj prefetch issued mid-phase-B (right after poll vmcnt), ~2.5 us
//         before its next forced vmcnt wait -> HBM latency fully hidden
//         (R9 issued it after S3, ~0.2 us before the next poll's vmcnt(0)).
//     (c) S3 deleted; red[] double-buffered per chain and xg[] per t-parity
//         keep it race-free -> 2 barriers/step instead of 4.
//     (d) publish-from-cell via shuffle pack (R10, verified) -> no hbst.
//     Rationale: R10 published earlier with zero effect on detection, and R6
//     showed slow steps even with payload pre-acked -> the period contains
//     serialized in-loop junk (prefetch exposure, out-store acks/RFO, barrier
//     convoys) coupled through vmcnt(0), not just publish->detect latency.
//     Exchange protocol, record format, init, overwrite/launch safety: R9
//     verbatim (transitive argument unaffected by S3 removal: records are
//     consumed into registers before each phase's tag-check passes).
// ---------------------------------------------------------------------------

typedef __attribute__((ext_vector_type(8))) __bf16 bf16x8;
typedef __attribute__((ext_vector_type(4))) __bf16 bf16x4;
typedef __attribute__((ext_vector_type(4))) float  f32x4;
typedef __attribute__((ext_vector_type(4))) unsigned u32x4;
typedef __attribute__((ext_vector_type(2))) unsigned u32x2;

#define TT 256
#define BBATCH 32

__device__ __forceinline__ __bf16 f2bf(float f){
  unsigned u = __builtin_bit_cast(unsigned, f);
  unsigned short r = (unsigned short)((u + 0x7fffu + ((u >> 16) & 1u)) >> 16);
  return __builtin_bit_cast(__bf16, r);
}
__device__ __forceinline__ float sigm(float x){
  x = fminf(fmaxf(x, -30.f), 30.f);
  return 1.f / (1.f + __expf(-x));
}
__device__ __forceinline__ float tanh_(float x){
  x = fminf(fmaxf(x, -15.f), 15.f);
  float e = __expf(2.f * x);
  return (e - 1.f) / (e + 1.f);
}

// --- coherent (MALL-level) access helpers: sc0 sc1 = bypass L1+L2 ----------
__device__ __forceinline__ u32x4 ld_b128_coh(const void* p){
  u32x4 v;
  asm volatile("global_load_dwordx4 %0, %1, off sc0 sc1"
               : "=v"(v) : "v"(p) : "memory");
  return v;
}
__device__ __forceinline__ void st_b128_coh(void* p, u32x4 v){
  asm volatile("global_store_dwordx4 %0, %1, off sc0 sc1"
               :: "v"(p), "v"(v) : "memory");
}

// ---------------------------------------------------------------------------
__global__ void k_meta(const void* __restrict__ mask,
                       const int* __restrict__ meta_a, const int* __restrict__ meta_c,
                       const float* __restrict__ emb_a, const float* __restrict__ emb_c,
                       const float* __restrict__ W1, const float* __restrict__ b1,
                       const float* __restrict__ W2,
                       float* __restrict__ c_out, int* __restrict__ len_out)
{
  __shared__ int s_bad;
  __shared__ float q_sh[32][128];
  __shared__ float hid[32][64];
  const int tid = threadIdx.x;
  if (tid == 0) s_bad = 0;
  __syncthreads();

  if (tid < 32){
    const unsigned char* m8 = (const unsigned char*)mask;
    int cnt = 0, seen0 = 0, bad = 0;
    for (int t = 0; t < TT; ++t){
      unsigned char v = m8[tid * TT + t];
      if (v > 1) bad = 1;
      if (v){ if (seen0) bad = 1; cnt++; } else seen0 = 1;
    }
    if (tid == 0 && cnt != TT) bad = 1;
    if (bad) atomicAdd(&s_bad, 1);
    len_out[tid] = cnt;
  }
  {
    int b = tid >> 3, p = tid & 7;
    int a = meta_a[b], c = meta_c[b];
    for (int i = 0; i < 16; ++i){
      int qi = p * 16 + i;
      q_sh[b][qi] = (qi < 64) ? emb_a[a * 64 + qi] : emb_c[c * 64 + (qi - 64)];
    }
  }
  __syncthreads();
  if (s_bad){
    if (tid < 32){
      const int* m32 = (const int*)mask;
      int cnt = 0;
      for (int t = 0; t < TT; ++t) if (m32[tid * TT + t]) cnt++;
      len_out[tid] = cnt;
    }
  }
  {
    int b = tid >> 3, kg = tid & 7;
    for (int k8 = 0; k8 < 8; ++k8){
      int k = kg * 8 + k8;
      float s = b1[k];
      for (int i = 0; i < 128; ++i) s += q_sh[b][i] * W1[i * 64 + k];
      hid[b][k] = tanhf(s);
    }
  }
  __syncthreads();
  if (tid < 32){
    float lg[8]; float mx = -1e30f;
    for (int n = 0; n < 8; ++n){
      float s = 0.f;
      for (int k = 0; k < 64; ++k) s += hid[tid][k] * W2[k * 8 + n];
      lg[n] = s; mx = fmaxf(mx, s);
    }
    float den = 0.f;
    for (int n = 0; n < 8; ++n){ lg[n] = expf(lg[n] - mx); den += lg[n]; }
    for (int n = 0; n < 8; ++n) c_out[tid * 8 + n] = lg[n] / den;
  }
}

// ---------------------------------------------------------------------------
__global__ void k_xbf(const float* __restrict__ x, __bf16* __restrict__ xb)
{
  int i = blockIdx.x * 256 + threadIdx.x;
  if (i >= 524288) return;
  f32x4 a = *(const f32x4*)(x + (size_t)i * 8);
  f32x4 b = *(const f32x4*)(x + (size_t)i * 8 + 4);
  bf16x8 o;
  #pragma unroll
  for (int j = 0; j < 4; ++j){ o[j] = f2bf(a[j]); o[4 + j] = f2bf(b[j]); }
  *(bf16x8*)(xb + (size_t)i * 8) = o;
}

// ---------------------------------------------------------------------------
__global__ void k_whhp(const float* __restrict__ whh_f, const float* __restrict__ whh_r,
                       __bf16* __restrict__ outp)
{
  int idx = blockIdx.x * 256 + threadIdx.x;
  int lane = idx & 63; int grp = idx >> 6;
  int n  = grp & 7;  grp >>= 3;
  int kt = grp & 3;  grp >>= 2;
  int wv = grp & 3;  grp >>= 2;
  int wg = grp & 127; int dir = (grp >> 7) & 1;
  int col = lane & 15, quad = lane >> 4;
  int gate = col >> 2, jj = col & 3;
  int g = gate * 512 + wg * 4 + jj;
  int k = (wv * 4 + kt) * 32 + quad * 8;
  const float* Wb = dir ? whh_r : whh_f;
  const float* s = Wb + ((size_t)n * 2048 + g) * 512 + k;
  f32x4 a = *(const f32x4*)s, b = *(const f32x4*)(s + 4);
  bf16x8 o;
  #pragma unroll
  for (int j = 0; j < 4; ++j){ o[j] = f2bf(a[j]); o[4 + j] = f2bf(b[j]); }
  *(bf16x8*)(outp + (size_t)idx * 8) = o;
}

// ---------------------------------------------------------------------------
__global__ void k_bias(const float* __restrict__ b_f, const float* __restrict__ b_r,
                       const float* __restrict__ cb, float* __restrict__ bm)
{
  int idx = blockIdx.x * 256 + threadIdx.x;
  int dir = idx >> 16; int b = (idx >> 11) & 31; int g = idx & 2047;
  const float* bb = dir ? b_r : b_f;
  float s = 0.f;
  #pragma unroll
  for (int n = 0; n < 8; ++n) s += cb[b * 8 + n] * bb[n * 2048 + g];
  bm[idx] = s;
}

// ---------------------------------------------------------------------------
__global__ void k_mixwih(const float* __restrict__ Wb, const float* __restrict__ cb,
                         __bf16* __restrict__ wmix)
{
  __shared__ float cs[256];
  int tid = threadIdx.x;
  cs[tid] = cb[tid];
  __syncthreads();
  int idx = blockIdx.x * 256 + tid;
  int g = idx >> 6, k8 = idx & 63;
  float src[8][8];
  #pragma unroll
  for (int n = 0; n < 8; ++n){
    const float* p = Wb + ((size_t)n * 2048 + g) * 512 + k8 * 8;
    f32x4 lo = *(const f32x4*)p, hi = *(const f32x4*)(p + 4);
    #pragma unroll
    for (int j = 0; j < 4; ++j){ src[n][j] = lo[j]; src[n][4 + j] = hi[j]; }
  }
  for (int b = 0; b < 32; ++b){
    float acc[8] = {0,0,0,0,0,0,0,0};
    #pragma unroll
    for (int n = 0; n < 8; ++n){
      float cn = cs[b * 8 + n];
      #pragma unroll
      for (int j = 0; j < 8; ++j) acc[j] += cn * src[n][j];
    }
    bf16x8 o;
    #pragma unroll
    for (int j = 0; j < 8; ++j) o[j] = f2bf(acc[j]);
    *(bf16x8*)(wmix + ((size_t)b * 2048 + g) * 512 + k8 * 8) = o;
  }
}

// ---------------------------------------------------------------------------
__global__ __launch_bounds__(256) void k_gemm(const __bf16* __restrict__ xb,
                                              const __bf16* __restrict__ wmix,
                                              float* __restrict__ xp)
{
  __shared__ __bf16 As[128][72];
  __shared__ __bf16 Bs[128][72];
  const int tid = threadIdx.x, lane = tid & 63, wv = tid >> 6;
  const int quad = lane >> 4, c16 = lane & 15;
  const int wm_ = wv >> 1, wn_ = wv & 1;
  const int b = blockIdx.x >> 5, tile = blockIdx.x & 31;
  const int m0 = (tile >> 4) * 128, n0 = (tile & 15) * 128;
  const __bf16* Ap = xb + (size_t)b * TT * 512;
  const __bf16* Bp = wmix + (size_t)b * 2048 * 512;
  float* Cp = xp + (size_t)b * TT * 2048;

  f32x4 acc[4][4];
  #pragma unroll
  for (int i = 0; i < 4; ++i)
    #pragma unroll
    for (int j = 0; j < 4; ++j) acc[i][j] = (f32x4){0,0,0,0};

  for (int k0 = 0; k0 < 512; k0 += 64){
    __syncthreads();
    #pragma unroll
    for (int it = 0; it < 4; ++it){
      int r = it * 32 + (tid >> 3), c = (tid & 7) * 8;
      *(bf16x8*)&As[r][c] = *(const bf16x8*)(Ap + (size_t)(m0 + r) * 512 + k0 + c);
      *(bf16x8*)&Bs[r][c] = *(const bf16x8*)(Bp + (size_t)(n0 + r) * 512 + k0 + c);
    }
    __syncthreads();
    #pragma unroll
    for (int kt = 0; kt < 2; ++kt){
      bf16x8 af[4], bfr[4];
      #pragma unroll
      for (int i = 0; i < 4; ++i){
        af[i]  = *(const bf16x8*)&As[wm_ * 64 + i * 16 + c16][kt * 32 + quad * 8];
        bfr[i] = *(const bf16x8*)&Bs[wn_ * 64 + i * 16 + c16][kt * 32 + quad * 8];
      }
      #pragma unroll
      for (int i = 0; i < 4; ++i)
        #pragma unroll
        for (int j = 0; j < 4; ++j)
          acc[i][j] = __builtin_amdgcn_mfma_f32_16x16x32_bf16(af[i], bfr[j], acc[i][j], 0, 0, 0);
    }
  }
  #pragma unroll
  for (int i = 0; i < 4; ++i)
    #pragma unroll
    for (int j = 0; j < 4; ++j){
      int colg = n0 + wn_ * 64 + j * 16 + c16;
      #pragma unroll
      for (int r = 0; r < 4; ++r){
        int row = m0 + wm_ * 64 + i * 16 + quad * 4 + r;
        Cp[(size_t)row * 2048 + colg] = acc[i][j][r];
      }
    }
}

// ---------------------------------------------------------------------------
// k_recur R12. Record buffers (256 KB total, at OFF_H):
//   rec[dir][chain g][buf][sample s 0..15][wg 0..127] = {h01, h23, tag, 0}
//     16 B; base offset ((dir*2+g)*2+buf) << 15.
// Protocol per chain (R5/R9): buf[t&1] with tag==t is the h input of step t.
//   Tag-0 zero records into buf0 at start; tag t+1 into buf[(t+1)&1] fired by
//   the cell wave (shuffle-packed, one sc0sc1 dwordx4, fire-and-forget).
//   Readers poll their own fragment records until all tags == t.
// Steady loop per step: {poll A, MFMA A, S2, cell A+publish A,
//                        poll B, pf-issue, MFMA B, S2, cell B+publish B}.
//   No S3 (red double-buffered per chain, xg per t-parity). out accumulated
//   in LDS, flushed once after the loop. Launch/overwrite safety: R9's
//   transitive argument (record reads complete into registers before each
//   phase's tag-check passes; publish of t+2 gated by poll of t+1).
// wg is XCD-swizzled (xproj/out 64B-line locality).
// ---------------------------------------------------------------------------
__global__ __launch_bounds__(256, 1) void k_recur(
    const __bf16* __restrict__ whhp,
    const float*  __restrict__ xproj,   // [2][32][256][2048]
    const float*  __restrict__ biasm,   // [2][32][2048]
    const float*  __restrict__ cb,      // [32][8]
    const int*    __restrict__ lens,    // [32]
    char* hrec,                         // record region (see above)
    float* __restrict__ out)            // [32][256][1024]
{
  const int tid = threadIdx.x, lane = tid & 63, wv = tid >> 6;
  const int quad = lane >> 4, c16 = lane & 15;
  const int bid = blockIdx.x, dir = bid >> 7;
  const int b7 = bid & 127;
  const int wg = ((b7 & 7) << 4) | (b7 >> 3);   // XCD-aware swizzle
  const int hidx0 = wg * 4;

  // basis-weight B fragments -> registers (logical-wg indexed)
  bf16x8 bfrag[4][8];
  {
    const __bf16* base = whhp + (size_t)((dir * 128 + wg) * 4 + wv) * 4 * (8 * 512);
    #pragma unroll
    for (int kt = 0; kt < 4; ++kt)
      #pragma unroll
      for (int n = 0; n < 8; ++n)
        bfrag[kt][n] = *(const bf16x8*)(base + (size_t)(kt * 8 + n) * 512 + lane * 8);
  }
  // c_batch columns for this lane's accumulator rows, per chain
  f32x4 ccv[2][8];
  #pragma unroll
  for (int g = 0; g < 2; ++g)
    #pragma unroll
    for (int n = 0; n < 8; ++n){
      f32x4 v;
      #pragma unroll
      for (int r = 0; r < 4; ++r) v[r] = cb[(g * 16 + quad * 4 + r) * 8 + n];
      ccv[g][n] = v;
    }

  // cell-thread state (tid < 64 = wave 0): sample s_ in chain, channel jj2
  const int s_ = tid >> 2, jj2 = tid & 3;
  float bias_gc[2][4] = {{0,0,0,0},{0,0,0,0}};
  int   mylen[2] = {0, 0};
  float cst[2] = {0.f, 0.f};
  if (tid < 64){
    #pragma unroll
    for (int g = 0; g < 2; ++g){
      #pragma unroll
      for (int gg = 0; gg < 4; ++gg)
        bias_gc[g][gg] = biasm[(size_t)(dir * 32 + g * 16 + s_) * 2048
                               + gg * 512 + hidx0 + jj2];
      mylen[g] = lens[g * 16 + s_];
    }
  }

  __shared__ float red[2][4][64][4];      // [chain][wave][lane][comp]
  __shared__ float xg[2][32][4][4];       // [t&1][sample][gate][ch]
  __shared__ float ob[2][16][257][4];     // [chain][sample][t(+pad)][ch]

  // init: lanes 192..223 publish zero-records (tag 0) into buf0, both chains
  if (tid >= 192 && tid < 224){
    int i = tid - 192, gi = i >> 4, sg = i & 15;
    u32x4 z = {0u, 0u, 0u, 0u};
    u32x4* wb = (u32x4*)(hrec + (((size_t)(dir * 2 + gi) * 2 + 0) << 15));
    st_b128_coh(wb + sg * 128 + wg, z);
  }

  // prefetch xproj for step 0 (normal cached load; waves 0-1)
  f32x4 pf = {0, 0, 0, 0};
  const int b_pf = tid >> 2, g_pf = tid & 3;
  if (tid < 128){
    int to0 = dir ? (TT - 1) : 0;
    pf = *(const f32x4*)(xproj + ((size_t)(dir * 32 + b_pf) * TT + to0) * 2048
                         + g_pf * 512 + hidx0);
  }

  // per-lane record indices (units of 16 B records), per kt: sample = c16,
  // channels (wv*4+kt)*32 + quad*8 .. +8 = records (wg0, wg0+1)
  int ridx[4];
  #pragma unroll
  for (int kt = 0; kt < 4; ++kt)
    ridx[kt] = c16 * 128 + (wv * 4 + kt) * 8 + quad * 2;

  for (int t = 0; t < TT; ++t){
    const int to = dir ? (TT - 1 - t) : t;
    const unsigned tgt = (unsigned)t;

    #pragma unroll
    for (int g = 0; g < 2; ++g){
      const u32x4* rb = (const u32x4*)(hrec
                        + (((size_t)(dir * 2 + g) * 2 + (t & 1)) << 15));

      // ---- poll-load this wave's fragment records until all tags == t ----
      u32x4 r0[4], r1[4];
      while (true){
        #pragma unroll
        for (int p = 0; p < 4; ++p){
          r0[p] = ld_b128_coh(rb + ridx[p]);
          r1[p] = ld_b128_coh(rb + ridx[p] + 1);
        }
        asm volatile("s_waitcnt vmcnt(0)"
                     : "+v"(r0[0]), "+v"(r0[1]), "+v"(r0[2]), "+v"(r0[3]),
                       "+v"(r1[0]), "+v"(r1[1]), "+v"(r1[2]), "+v"(r1[3])
                     :: "memory");
        unsigned bad = 0;
        #pragma unroll
        for (int p = 0; p < 4; ++p)
          bad |= (r0[p][2] ^ tgt) | (r1[p][2] ^ tgt);
        if (__all((int)(bad == 0u))) break;
      }
      bf16x8 af[4];
      #pragma unroll
      for (int p = 0; p < 4; ++p){
        u32x4 w = {r0[p][0], r0[p][1], r1[p][0], r1[p][1]};
        af[p] = __builtin_bit_cast(bf16x8, w);
      }

      // phase A: bank this step's xproj (pf holds xproj(t)) into xg[t&1]
      if (g == 0 && tid < 128)
        *(f32x4*)&xg[t & 1][b_pf][g_pf][0] = pf;
      // phase B: issue next step's xproj prefetch NOW -> ~2.5 us of cover
      // (next forced vmcnt wait is step t+1 phase A's poll)
      if (g == 1 && t < TT - 1 && tid < 128){
        int ton = dir ? (TT - 2 - t) : (t + 1);
        pf = *(const f32x4*)(xproj + ((size_t)(dir * 32 + b_pf) * TT + ton) * 2048
                             + g_pf * 512 + hidx0);
      }

      // ---- MFMA: h(16 samples) x basis weights, mix over basis ----
      f32x4 acc[8];
      #pragma unroll
      for (int n = 0; n < 8; ++n) acc[n] = (f32x4){0,0,0,0};
      #pragma unroll
      for (int kt = 0; kt < 4; ++kt)
        #pragma unroll
        for (int n = 0; n < 8; ++n)
          acc[n] = __builtin_amdgcn_mfma_f32_16x16x32_bf16(af[kt], bfrag[kt][n], acc[n], 0, 0, 0);
      f32x4 mix = {0,0,0,0};
      #pragma unroll
      for (int n = 0; n < 8; ++n) mix += ccv[g][n] * acc[n];
      *(f32x4*)&red[g][wv][lane][0] = mix;
      __syncthreads();   // S2: red[g]/xg ready

      // ---- cell (wave 0): 16 samples x 4 channels; publish immediately ----
      // No S3: other waves proceed to the next phase's poll; they write only
      // red[g^1] / xg[(t+1)&1] before the next barrier, never red[g]/xg[t&1].
      if (tid < 64){
        const int qp = s_ >> 2, rg = s_ & 3;
        float gv[4];
        #pragma unroll
        for (int gg = 0; gg < 4; ++gg){
          int li = qp * 16 + gg * 4 + jj2;
          float s = red[g][0][li][rg] + red[g][1][li][rg]
                  + red[g][2][li][rg] + red[g][3][li][rg];
          gv[gg] = s + xg[t & 1][g * 16 + s_][gg][jj2] + bias_gc[g][gg];
        }
        float i_ = sigm(gv[0]);
        float f_ = sigm(gv[1]);
        float g_ = tanh_(gv[2]);
        float o_ = sigm(gv[3]);
        bool valid = (to < mylen[g]);
        float cy = valid ? (f_ * cst[g] + i_ * g_) : 0.f;
        float hy = valid ? (o_ * tanh_(cy)) : 0.f;
        cst[g] = cy;
        ob[g][s_][t][jj2] = hy;

        // shuffle-pack the 16 B record {h01,h23,tag,0} and fire it now
        unsigned hu = (unsigned)__builtin_bit_cast(unsigned short, f2bf(hy));
        unsigned hx = __shfl_xor(hu, 1, 64);
        unsigned dpair = (jj2 & 1) ? (hx | (hu << 16)) : (hu | (hx << 16));
        unsigned dothr = __shfl_xor(dpair, 2, 64);
        if (jj2 == 0){
          u32x4 rec = {dpair, dothr, (unsigned)(t + 1), 0u};
          u32x4* wb = (u32x4*)(hrec
                      + (((size_t)(dir * 2 + g) * 2 + ((t + 1) & 1)) << 15));
          st_b128_coh(wb + s_ * 128 + wg, rec);
        }
      }
    }
  }

  // ---- one-time out flush: 128 KB LDS -> global ----
  __syncthreads();
  for (int i = tid; i < 8192; i += 256){
    int t_ = i & 255, sg = (i >> 8) & 15, g2 = i >> 12;
    int tow = dir ? (TT - 1 - t_) : t_;
    *(f32x4*)(out + ((size_t)(g2 * 16 + sg) * TT + tow) * 1024
              + dir * 512 + hidx0)
        = *(f32x4*)&ob[g2][sg][t_][0];
  }
}

// ---------------------------------------------------------------------------
extern "C" void kernel_launch(void* const* d_in, const int* in_sizes, int n_in,
                              void* d_out, int out_size, void* d_ws, size_t ws_size,
                              hipStream_t stream)
{
  const float* x      = (const float*)d_in[0];
  const void*  mask   = d_in[1];
  const int*   meta_a = (const int*)d_in[2];
  const int*   meta_c = (const int*)d_in[3];
  const float* emb_a  = (const float*)d_in[4];
  const float* emb_c  = (const float*)d_in[5];
  const float* P_W1   = (const float*)d_in[6];
  const float* P_b1   = (const float*)d_in[7];
  const float* P_W2   = (const float*)d_in[8];
  const float* W_ih   = (const float*)d_in[9];
  const float* W_hh   = (const float*)d_in[10];
  const float* bias_f = (const float*)d_in[11];
  const float* W_ih_r = (const float*)d_in[12];
  const float* W_hh_r = (const float*)d_in[13];
  const float* bias_r = (const float*)d_in[14];
  float* out = (float*)d_out;
  char* ws = (char*)d_ws;

  constexpr size_t OFF_C     = 0;           //   1 KB  c_batch
  constexpr size_t OFF_LEN   = 1024;        //  128 B  lengths
  constexpr size_t OFF_BIAS  = 4096;        //  512 KB mixed biases
  constexpr size_t OFF_H     = 528384;      //  256 KB tagged h records
  constexpr size_t OFF_WHHP  = 790528;      // 33.5 MB basis Whh fragments
  constexpr size_t OFF_XBF   = 34344960;    //  8.4 MB x bf16
  constexpr size_t OFF_WIHM  = 42733568;    //   67 MB mixed Wih (per-dir reuse)
  constexpr size_t OFF_XPROJ = 109842432;   //  134 MB xproj f32 (both dirs)
  constexpr size_t WS_NEED   = 244060160;
  if (ws_size < WS_NEED) return;

  float*   c_b   = (float*)(ws + OFF_C);
  int*     lens  = (int*)(ws + OFF_LEN);
  float*   biasm = (float*)(ws + OFF_BIAS);
  char*    hrec  = (char*)(ws + OFF_H);
  __bf16*  whhp  = (__bf16*)(ws + OFF_WHHP);
  __bf16*  xbf   = (__bf16*)(ws + OFF_XBF);
  __bf16*  wihm  = (__bf16*)(ws + OFF_WIHM);
  float*   xproj = (float*)(ws + OFF_XPROJ);

  k_meta<<<1, 256, 0, stream>>>(mask, meta_a, meta_c, emb_a, emb_c,
                                P_W1, P_b1, P_W2, c_b, lens);
  k_xbf<<<2048, 256, 0, stream>>>(x, xbf);
  k_whhp<<<8192, 256, 0, stream>>>(W_hh, W_hh_r, whhp);
  k_bias<<<512, 256, 0, stream>>>(bias_f, bias_r, c_b, biasm);
  for (int dir = 0; dir < 2; ++dir){
    k_mixwih<<<512, 256, 0, stream>>>(dir ? W_ih_r : W_ih, c_b, wihm);
    k_gemm<<<1024, 256, 0, stream>>>(xbf, wihm,
                                     xproj + (size_t)dir * 32 * TT * 2048);
  }
  k_recur<<<256, 256, 0, stream>>>(whhp, xproj, biasm, c_b, lens, hrec, out);
}